// Round 6
// baseline (43486.142 us; speedup 1.0000x reference)
//
#include <hip/hip_runtime.h>
#include <hip/hip_bf16.h>

// LSTM T=2048, B=64, D=512, H=512.
// Batch-decomposed persistent kernel: the recurrence is row-independent, so
// B=64 splits into 4 groups of 16 rows. Each group = 32 blocks x 128 thr
// (2 waves, 8 hidden cols/wave). If the 32 blocks of a group share one XCD
// (detected via HW_REG_XCC_ID at runtime; strict validation), all h-exchange
// runs at XCD-L2 latency via workgroup-scope atomic RMWs (atomics always
// execute at L2, bypassing L1 -> XCD-coherent). Otherwise SAFE fallback:
// identical math with agent-scope (sc1) atomics. Workers self-heat (FMA burn
// in the poll loop) + dedicated heater blocks keep DPM clocks up (R5: +40%).

#define T_N 2048
#define B_N 64
#define D_N 512
#define H_N 512
#define NTHR 128
#define TOT_BLK 256
#define GR_N 4
#define GB_N 32
#define NWORK (GR_N * GB_N)

#define STACK_ELEMS ((size_t)T_N * B_N * H_N)
#define HT_OFF STACK_ELEMS
#define CT_OFF (STACK_ELEMS + (size_t)B_N * H_N)

// ws layout (bytes)
#define WS_XCNT 0
#define WS_TOT 64
#define WS_MODE 68
#define WS_SRANK 72
#define WS_DONE 76
#define WS_VIOL 80
#define WS_FLAGS 8192    // + g*4096 + (m*2+w)*64
#define WS_RING 65536    // + g*32768 + slot*16384 + m*512 + row*32 + col*2
#define WS_XB 1048576

typedef __attribute__((ext_vector_type(4))) float f32x4;
typedef __attribute__((ext_vector_type(8))) short bf16x8;

__device__ __forceinline__ unsigned short f2bf(float f) {
  union { __hip_bfloat16 h; unsigned short u; } u;
  u.h = __float2bfloat16(f);
  return u.u;
}
__device__ __forceinline__ float bf2f(unsigned short us) {
  union { unsigned u32; float f; } x;
  x.u32 = ((unsigned)us) << 16;
  return x.f;
}
__device__ __forceinline__ float sigf(float x) { return 1.0f / (1.0f + __expf(-x)); }
__device__ __forceinline__ float tanhfast(float x) { return 1.0f - 2.0f / (__expf(2.0f * x) + 1.0f); }

__global__ void init_ws_kernel(unsigned* ws32) {
  int i = blockIdx.x * blockDim.x + threadIdx.x;
  if (i < 65536) ws32[i] = 0u;  // zero first 256 KB (bootstrap+flags+rings)
}

__global__ void xconv_kernel(const float* __restrict__ X, unsigned short* __restrict__ Xb) {
  size_t i = ((size_t)blockIdx.x * blockDim.x + threadIdx.x) * 8;
  float4 v0 = *(const float4*)(X + i);
  float4 v1 = *(const float4*)(X + i + 4);
  bf16x8 o;
  o[0] = (short)f2bf(v0.x); o[1] = (short)f2bf(v0.y);
  o[2] = (short)f2bf(v0.z); o[3] = (short)f2bf(v0.w);
  o[4] = (short)f2bf(v1.x); o[5] = (short)f2bf(v1.y);
  o[6] = (short)f2bf(v1.z); o[7] = (short)f2bf(v1.w);
  *(bf16x8*)(Xb + i) = o;
}

__device__ __forceinline__ void load_x_tile(const unsigned short* Xb, const float* X,
                                            int t, int grow, int kg, bf16x8 (&xa)[16]) {
  if (Xb) {
    const unsigned short* xp = Xb + ((size_t)t * B_N + grow) * D_N + kg;
#pragma unroll
    for (int kk = 0; kk < 16; ++kk) xa[kk] = *(const bf16x8*)(xp + kk * 32);
  } else {
    const float* xp = X + ((size_t)t * B_N + grow) * D_N + kg;
#pragma unroll
    for (int kk = 0; kk < 16; ++kk) {
      float4 v0 = *(const float4*)(xp + kk * 32);
      float4 v1 = *(const float4*)(xp + kk * 32 + 4);
      bf16x8 a;
      a[0] = (short)f2bf(v0.x); a[1] = (short)f2bf(v0.y);
      a[2] = (short)f2bf(v0.z); a[3] = (short)f2bf(v0.w);
      a[4] = (short)f2bf(v1.x); a[5] = (short)f2bf(v1.y);
      a[6] = (short)f2bf(v1.z); a[7] = (short)f2bf(v1.w);
      xa[kk] = a;
    }
  }
}

template <int SCOPE>
__device__ void worker_body(int g, int m,
    const float* X, const unsigned short* Xb,
    const float* Wf, const float* bF, const float* Wi, const float* bI,
    const float* Wg, const float* bG, const float* Wo, const float* bO,
    unsigned char* wsb, float* out, unsigned short* Wl) {
  const int tid = threadIdx.x;
  const int w = tid >> 6;          // wave 0/1
  const int lane = tid & 63;
  const int l16 = lane & 15;
  const int g16 = lane >> 4;
  const int cc = l16 & 7;
  const bool lo = (l16 < 8);

  // Stage W per wave (2 passes through ONE 64KB buffer -> LDS is clobbered,
  // forcing wb into VGPRs). Wave p's 32 gate cols = 4 gates x 8 hidden cols
  // at base m*16 + p*8. Fragment-linear layout (conflict-free b128 reads).
  bf16x8 wb0[32], wb1[32];
  for (int p = 0; p < 2; ++p) {
    for (int idx = tid; idx < 32768; idx += NTHR) {
      int k = idx >> 5;
      int cl = idx & 31;
      const float* wsrc = (cl < 8) ? Wf : (cl < 16) ? Wi : (cl < 24) ? Wg : Wo;
      float v = wsrc[(size_t)k * H_N + m * 16 + p * 8 + (cl & 7)];
      int pos = ((k >> 5) * 1024) + ((cl >> 4) * 512) + (((k >> 3) & 3) * 128) + ((cl & 15) * 8) + (k & 7);
      Wl[pos] = f2bf(v);
    }
    __syncthreads();
    if (w == p) {
#pragma unroll
      for (int K = 0; K < 32; ++K) {
        wb0[K] = *(const bf16x8*)&Wl[K * 1024 + lane * 8];
        wb1[K] = *(const bf16x8*)&Wl[K * 1024 + 512 + lane * 8];
      }
    }
    __syncthreads();
  }

  const int c0w = m * 16 + w * 8;
  const float bias0 = lo ? bF[c0w + cc] : bI[c0w + cc];
  const float bias1 = lo ? bG[c0w + cc] : bO[c0w + cc];

  unsigned z32 = 0;
  asm volatile("" : "+v"(z32));   // opaque zero: keep fetch_add as a real RMW
  unsigned long long z64 = z32;

  const int grow = g * 16 + l16;  // global batch row for A fragments
  const int kg = 8 * g16;

  unsigned* flg = (unsigned*)(wsb + WS_FLAGS + (size_t)g * 4096);
  unsigned char* ringg = wsb + WS_RING + (size_t)g * 32768;

  float cst[4] = {0.f, 0.f, 0.f, 0.f};
  float hT_local[4] = {0.f, 0.f, 0.f, 0.f};
  float heat = 1.0f + (float)tid * 1e-7f;
  const float hm = 0.99993f, hc = 1e-8f;

  bf16x8 xa[16];
  load_x_tile(Xb, X, 0, grow, kg, xa);

  for (int t = 0; t < T_N; ++t) {
    const int slotR = (t + 1) & 1;
    const int slotW = t & 1;

    // ---- x MFMAs (prefetched; overlaps other waves' tails)
    f32x4 x0a = {0,0,0,0}, x0b = {0,0,0,0}, x1a = {0,0,0,0}, x1b = {0,0,0,0};
#pragma unroll
    for (int kk = 0; kk < 8; ++kk) {
      x0a = __builtin_amdgcn_mfma_f32_16x16x32_bf16(xa[kk], wb0[kk], x0a, 0, 0, 0);
      x1a = __builtin_amdgcn_mfma_f32_16x16x32_bf16(xa[kk], wb1[kk], x1a, 0, 0, 0);
    }
#pragma unroll
    for (int kk = 8; kk < 16; ++kk) {
      x0b = __builtin_amdgcn_mfma_f32_16x16x32_bf16(xa[kk], wb0[kk], x0b, 0, 0, 0);
      x1b = __builtin_amdgcn_mfma_f32_16x16x32_bf16(xa[kk], wb1[kk], x1b, 0, 0, 0);
    }

    // ---- poll group flags (lane l watches wave-flag l). RMW => L1-proof.
    // FMA burn between checks keeps this CU hot for DPM (workers self-heat).
    if (t > 0) {
      const unsigned tgt = (unsigned)t;
      unsigned* fp = (unsigned*)((unsigned char*)flg + (size_t)lane * 64);
      long guard = 0;
      float h0 = heat, h1 = heat + 0.1f, h2 = heat + 0.2f, h3 = heat + 0.3f;
      for (;;) {
        unsigned v = __hip_atomic_fetch_add(fp, z32, __ATOMIC_RELAXED, SCOPE);
        if (__all((int)(v >= tgt))) break;
#pragma unroll
        for (int j = 0; j < 16; ++j) {
          h0 = __builtin_fmaf(h0, hm, hc); h1 = __builtin_fmaf(h1, hm, hc);
          h2 = __builtin_fmaf(h2, hm, hc); h3 = __builtin_fmaf(h3, hm, hc);
        }
        if (++guard > (1l << 22)) break;  // bail-out: no deadlock-hang
      }
      heat = h0 + h1 + h2 + h3;
      asm volatile("" : "+v"(heat));      // sink + compiler barrier
      asm volatile("" ::: "memory");
    }

    // ---- h loads: 32 independent RMW-reads (execute at L2), one batch
    unsigned long long hq0[16], hq1[16];
    {
      unsigned char* rb = ringg + (size_t)slotR * 16384;
#pragma unroll
      for (int kk = 0; kk < 16; ++kk) {
        unsigned long long* p =
            (unsigned long long*)(rb + (size_t)(2 * kk + (g16 >> 1)) * 512 + l16 * 32 + (g16 & 1) * 16);
        hq0[kk] = __hip_atomic_fetch_add(p, z64, __ATOMIC_RELAXED, SCOPE);
        hq1[kk] = __hip_atomic_fetch_add(p + 1, z64, __ATOMIC_RELAXED, SCOPE);
      }
    }

    // ---- h MFMAs
    f32x4 h0a = {0,0,0,0}, h0b = {0,0,0,0}, h1a = {0,0,0,0}, h1b = {0,0,0,0};
#pragma unroll
    for (int kk = 0; kk < 8; ++kk) {
      union { unsigned long long q[2]; bf16x8 v; } u;
      u.q[0] = hq0[kk]; u.q[1] = hq1[kk];
      h0a = __builtin_amdgcn_mfma_f32_16x16x32_bf16(u.v, wb0[16 + kk], h0a, 0, 0, 0);
      h1a = __builtin_amdgcn_mfma_f32_16x16x32_bf16(u.v, wb1[16 + kk], h1a, 0, 0, 0);
    }
#pragma unroll
    for (int kk = 8; kk < 16; ++kk) {
      union { unsigned long long q[2]; bf16x8 v; } u;
      u.q[0] = hq0[kk]; u.q[1] = hq1[kk];
      h0b = __builtin_amdgcn_mfma_f32_16x16x32_bf16(u.v, wb0[16 + kk], h0b, 0, 0, 0);
      h1b = __builtin_amdgcn_mfma_f32_16x16x32_bf16(u.v, wb1[16 + kk], h1b, 0, 0, 0);
    }
    f32x4 m0v = (x0a + x0b) + (h0a + h0b);
    f32x4 m1v = (x1a + x1b) + (h1a + h1b);

    // ---- gates + cell update (acc rows 4*g16+r local; cols l16)
    float hv[4];
#pragma unroll
    for (int r = 0; r < 4; ++r) {
      float m0 = m0v[r] + bias0;
      float m1 = m1v[r] + bias1;
      float p0 = __shfl_xor(m0, 8, 64);
      float p1 = __shfl_xor(m1, 8, 64);
      float fv = lo ? m0 : p0;
      float iv = lo ? p0 : m0;
      float gv = lo ? m1 : p1;
      float ov = lo ? p1 : m1;
      float f = sigf(fv), i = sigf(iv), gg2 = tanhfast(gv), o = sigf(ov);
      float c = f * cst[r] + i * gg2;
      cst[r] = c;
      hv[r] = o * tanhfast(c);
    }

    // ---- publish h_t (atomic exchange -> lands in L2; packed bf16 pairs)
    {
      unsigned char* wbp = ringg + (size_t)slotW * 16384 + (size_t)m * 512;
#pragma unroll
      for (int r = 0; r < 4; ++r) {
        int row = 4 * g16 + r;
        unsigned short hb = f2bf(hv[r]);
        unsigned opp = __shfl_xor((unsigned)hb, 1, 64);
        if (lo && (cc & 1) == 0) {
          unsigned pack = (unsigned)hb | (opp << 16);
          __hip_atomic_exchange((unsigned*)(wbp + row * 32 + (w * 8 + cc) * 2), pack,
                                __ATOMIC_RELAXED, SCOPE);
        }
      }
    }

    // ---- release: drain own ring stores, then set this wave's flag
    asm volatile("s_waitcnt vmcnt(0)" ::: "memory");
    if (lane == 0 && t < T_N - 1) {
      __hip_atomic_exchange(flg + (size_t)(m * 2 + w) * 16, (unsigned)(t + 1),
                            __ATOMIC_RELAXED, SCOPE);
    }

    // ---- prefetch next x tile (latency hides under next step)
    if (t + 1 < T_N) load_x_tile(Xb, X, t + 1, grow, kg, xa);

    // ---- consumer-side out[t-1] full-row write (block m<16 owns row m)
    if (w == 0 && m < 16 && t > 0 && l16 == m) {
      float* oprev = out + (size_t)(t - 1) * (B_N * H_N) + (size_t)(g * 16 + m) * H_N;
#pragma unroll
      for (int kk = 0; kk < 16; ++kk) {
        union { unsigned long long q[2]; bf16x8 v; } u;
        u.q[0] = hq0[kk]; u.q[1] = hq1[kk];
        float4 f0, f1;
        f0.x = bf2f((unsigned short)u.v[0]); f0.y = bf2f((unsigned short)u.v[1]);
        f0.z = bf2f((unsigned short)u.v[2]); f0.w = bf2f((unsigned short)u.v[3]);
        f1.x = bf2f((unsigned short)u.v[4]); f1.y = bf2f((unsigned short)u.v[5]);
        f1.z = bf2f((unsigned short)u.v[6]); f1.w = bf2f((unsigned short)u.v[7]);
        *(float4*)(oprev + 32 * kk + kg) = f0;
        *(float4*)(oprev + 32 * kk + kg + 4) = f1;
      }
    }

    // ---- final step: producer writes out[T-1] + keeps hT
    if (t == T_N - 1) {
      float* obase = out + (size_t)t * (B_N * H_N);
#pragma unroll
      for (int r = 0; r < 4; ++r) {
        int row2 = g * 16 + 4 * g16 + r;
        if (lo) obase[(size_t)row2 * H_N + c0w + cc] = hv[r];
        hT_local[r] = hv[r];
      }
    }
  }

  if (lo) {
#pragma unroll
    for (int r = 0; r < 4; ++r) {
      int row2 = g * 16 + 4 * g16 + r;
      out[HT_OFF + (size_t)row2 * H_N + c0w + cc] = hT_local[r];
      out[CT_OFF + (size_t)row2 * H_N + c0w + cc] = cst[r];
    }
  }
  if (tid == 0)
    __hip_atomic_fetch_add((unsigned*)(wsb + WS_DONE), 1u, __ATOMIC_RELAXED,
                           __HIP_MEMORY_SCOPE_AGENT);
}

__global__ __launch_bounds__(NTHR, 1) void lstm_kernel(
    const float* __restrict__ X, const unsigned short* __restrict__ Xb,
    const float* __restrict__ Wf, const float* __restrict__ bF,
    const float* __restrict__ Wi, const float* __restrict__ bI,
    const float* __restrict__ Wg, const float* __restrict__ bG,
    const float* __restrict__ Wo, const float* __restrict__ bO,
    unsigned char* wsb, float* __restrict__ out) {
  __shared__ unsigned short Wl[32768];  // 64 KB staging (clobbered per pass)
  __shared__ int sRole, sG, sM;
  const int tid = threadIdx.x;

  if (tid == 0) {
    unsigned* xcnt = (unsigned*)(wsb + WS_XCNT);
    unsigned x;
    asm volatile("s_getreg_b32 %0, hwreg(20, 0, 32)" : "=s"(x));  // HW_REG_XCC_ID
    if (x >= 8u)
      __hip_atomic_fetch_or((unsigned*)(wsb + WS_VIOL), 1u, __ATOMIC_RELAXED, __HIP_MEMORY_SCOPE_AGENT);
    unsigned xc = x & 7u;
    unsigned rank = __hip_atomic_fetch_add(&xcnt[xc], 1u, __ATOMIC_RELAXED, __HIP_MEMORY_SCOPE_AGENT);
    unsigned tot = __hip_atomic_fetch_add((unsigned*)(wsb + WS_TOT), 1u, __ATOMIC_ACQ_REL, __HIP_MEMORY_SCOPE_AGENT);
    if (tot == TOT_BLK - 1) {
      // strict validation: FAST only if every bucket is exactly 32 (true
      // XCD round-robin). Any garbage hwreg read falls back to SAFE.
      bool ok = __hip_atomic_load((unsigned*)(wsb + WS_VIOL), __ATOMIC_RELAXED, __HIP_MEMORY_SCOPE_AGENT) == 0u;
      for (int i = 0; i < 8; ++i)
        ok = ok && (__hip_atomic_load(&xcnt[i], __ATOMIC_RELAXED, __HIP_MEMORY_SCOPE_AGENT) == 32u);
      __hip_atomic_exchange((unsigned*)(wsb + WS_MODE), ok ? 1u : 2u, __ATOMIC_RELAXED, __HIP_MEMORY_SCOPE_AGENT);
    }
    unsigned mval;
    long gd = 0;
    for (;;) {
      mval = __hip_atomic_load((unsigned*)(wsb + WS_MODE), __ATOMIC_RELAXED, __HIP_MEMORY_SCOPE_AGENT);
      if (mval) break;
      __builtin_amdgcn_s_sleep(8);
      if (++gd > (1l << 24)) { mval = 2u; break; }
    }
    int role = 0, gg = 0, mm = 0;
    if (mval == 1u) {
      if (xc < GR_N && rank < GB_N) { role = 1; gg = (int)xc; mm = (int)rank; }
    } else {
      unsigned sr = __hip_atomic_fetch_add((unsigned*)(wsb + WS_SRANK), 1u, __ATOMIC_RELAXED, __HIP_MEMORY_SCOPE_AGENT);
      if (sr < (unsigned)NWORK) { role = 2; gg = (int)(sr >> 5); mm = (int)(sr & 31); }
    }
    sRole = role; sG = gg; sM = mm;
  }
  __syncthreads();
  const int role = sRole, g = sG, m = sM;

  if (role == 1) {
    worker_body<__HIP_MEMORY_SCOPE_WORKGROUP>(g, m, X, Xb, Wf, bF, Wi, bI, Wg, bG, Wo, bO, wsb, out, Wl);
  } else if (role == 2) {
    worker_body<__HIP_MEMORY_SCOPE_AGENT>(g, m, X, Xb, Wf, bF, Wi, bI, Wg, bG, Wo, bO, wsb, out, Wl);
  } else {
    // HEATER: hold DPM clocks up; exit when all 128 workers are done.
    float a = 1.0f + (float)(blockIdx.x * NTHR + tid) * 1e-7f;
    const float hm = 0.99993f, hc = 1e-8f;
    for (long i = 0;; ++i) {
#pragma unroll
      for (int j = 0; j < 512; ++j) a = __builtin_fmaf(a, hm, hc);
      if ((i & 7) == 0) {
        unsigned d = __hip_atomic_load((unsigned*)(wsb + WS_DONE), __ATOMIC_RELAXED, __HIP_MEMORY_SCOPE_AGENT);
        if (d >= (unsigned)NWORK) break;
        if (i > (1l << 22)) break;  // bail-out: no deadlock-hang
      }
    }
    asm volatile("" :: "v"(a));
  }
}

extern "C" void kernel_launch(void* const* d_in, const int* in_sizes, int n_in,
                              void* d_out, int out_size, void* d_ws, size_t ws_size,
                              hipStream_t stream) {
  const float* X  = (const float*)d_in[0];
  const float* Wf = (const float*)d_in[1];
  const float* bF = (const float*)d_in[2];
  const float* Wi = (const float*)d_in[3];
  const float* bI = (const float*)d_in[4];
  const float* Wg = (const float*)d_in[5];
  const float* bG = (const float*)d_in[6];
  const float* Wo = (const float*)d_in[7];
  const float* bO = (const float*)d_in[8];
  float* out = (float*)d_out;

  unsigned char* ws = (unsigned char*)d_ws;
  const size_t need_xb = WS_XB + (size_t)T_N * B_N * D_N * 2;  // ~129 MB
  unsigned short* Xb = (ws_size >= need_xb) ? (unsigned short*)(ws + WS_XB) : nullptr;

  init_ws_kernel<<<dim3(256), dim3(256), 0, stream>>>((unsigned*)ws);
  if (Xb) {
    xconv_kernel<<<dim3((T_N * B_N * D_N) / 8 / 256), dim3(256), 0, stream>>>(X, Xb);
  }
  lstm_kernel<<<dim3(TOT_BLK), dim3(NTHR), 0, stream>>>(
      X, Xb, Wf, bF, Wi, bI, Wg, bG, Wo, bO, ws, out);
}

// Round 7
// 23932.805 us; speedup vs baseline: 1.8170x; 1.8170x over previous
//
#include <hip/hip_runtime.h>
#include <hip/hip_bf16.h>

// LSTM T=2048, B=64, D=512, H=512. Persistent kernel: 256 blocks x 256 thr.
// Blocks 0..63 = workers (block b owns hidden cols [8b,8b+8) -> 32 gate cols;
// W in 256 VGPRs/lane; c-state in regs). Blocks 64..255 = heaters (hold DPM
// clocks; R5 measured +40%). h exchange: TAGGED-WORD single-hop ring --
// each u32 = bf16 | (step_tag<<16). Producers store (relaxed sc1) with NO
// drain and NO flag; consumers poll the data words directly until tagged.
// 2-slot ring + tag equality is skew-safe (producer <= 1 step ahead by the
// read-before-write dependency). No atomic RMWs anywhere (R6 lesson: RMW
// polling = 20 GB writeback storm).

#define T_N 2048
#define B_N 64
#define D_N 512
#define H_N 512
#define NBLK 64
#define NHEAT 192
#define CPB 8
#define GCPB 32
#define NTHR 256

#define STACK_ELEMS ((size_t)T_N * B_N * H_N)   // 67108864
#define HT_OFF STACK_ELEMS
#define CT_OFF (STACK_ELEMS + (size_t)B_N * H_N)

// ws layout (bytes)
#define WS_DONE 0
#define WS_RING 32768            // u32 ring[2][64 prod][64 row][8 col] = 256 KB
#define WS_XB   524288
#define RING_SLOT_U32 32768      // 64*64*8

typedef __attribute__((ext_vector_type(4))) float f32x4;
typedef __attribute__((ext_vector_type(8))) short bf16x8;

__device__ __forceinline__ unsigned short f2bf(float f) {
  union { __hip_bfloat16 h; unsigned short u; } u;
  u.h = __float2bfloat16(f);
  return u.u;
}
__device__ __forceinline__ float bf2f(unsigned short us) {
  union { unsigned u32; float f; } x;
  x.u32 = ((unsigned)us) << 16;
  return x.f;
}
__device__ __forceinline__ float sigf(float x) { return 1.0f / (1.0f + __expf(-x)); }
__device__ __forceinline__ float tanhfast(float x) { return 1.0f - 2.0f / (__expf(2.0f * x) + 1.0f); }

__global__ void init_ws_kernel(unsigned* ws32) {
  int i = blockIdx.x * blockDim.x + threadIdx.x;
  if (i < 131072) ws32[i] = 0u;  // zero first 512 KB (done + ring)
}

__global__ void xconv_kernel(const float* __restrict__ X, unsigned short* __restrict__ Xb) {
  size_t i = ((size_t)blockIdx.x * blockDim.x + threadIdx.x) * 8;
  float4 v0 = *(const float4*)(X + i);
  float4 v1 = *(const float4*)(X + i + 4);
  bf16x8 o;
  o[0] = (short)f2bf(v0.x); o[1] = (short)f2bf(v0.y);
  o[2] = (short)f2bf(v0.z); o[3] = (short)f2bf(v0.w);
  o[4] = (short)f2bf(v1.x); o[5] = (short)f2bf(v1.y);
  o[6] = (short)f2bf(v1.z); o[7] = (short)f2bf(v1.w);
  *(bf16x8*)(Xb + i) = o;
}

__device__ __forceinline__ void load_x_tile(const unsigned short* Xb, const float* X,
                                            int t, int arow, int kg, bf16x8 (&xa)[16]) {
  if (Xb) {
    const unsigned short* xp = Xb + ((size_t)t * B_N + arow) * D_N + kg;
#pragma unroll
    for (int kk = 0; kk < 16; ++kk) xa[kk] = *(const bf16x8*)(xp + kk * 32);
  } else {
    const float* xp = X + ((size_t)t * B_N + arow) * D_N + kg;
#pragma unroll
    for (int kk = 0; kk < 16; ++kk) {
      float4 v0 = *(const float4*)(xp + kk * 32);
      float4 v1 = *(const float4*)(xp + kk * 32 + 4);
      bf16x8 a;
      a[0] = (short)f2bf(v0.x); a[1] = (short)f2bf(v0.y);
      a[2] = (short)f2bf(v0.z); a[3] = (short)f2bf(v0.w);
      a[4] = (short)f2bf(v1.x); a[5] = (short)f2bf(v1.y);
      a[6] = (short)f2bf(v1.z); a[7] = (short)f2bf(v1.w);
      xa[kk] = a;
    }
  }
}

__global__ __launch_bounds__(NTHR, 1) void lstm_kernel(
    const float* __restrict__ X, const unsigned short* __restrict__ Xb,
    const float* __restrict__ Wf, const float* __restrict__ bF,
    const float* __restrict__ Wi, const float* __restrict__ bI,
    const float* __restrict__ Wg, const float* __restrict__ bG,
    const float* __restrict__ Wo, const float* __restrict__ bO,
    unsigned char* wsb, float* __restrict__ out) {
  __shared__ unsigned short Wl[GCPB * (D_N + H_N)];  // 64 KB staging (workers)

  const int tid = threadIdx.x;
  const int blk = blockIdx.x;
  const int lane = tid & 63;

  if (blk >= NBLK) {
    // ---------------- HEATER: hold DPM clocks; exit on done-counter ----------
    const unsigned* dp = (const unsigned*)(wsb + WS_DONE);
    float a = 1.0f + (float)(blk * NTHR + tid) * 1e-7f;
    const float hm = 0.99993f, hc = 1e-8f;
    for (long i = 0;; ++i) {
#pragma unroll
      for (int j = 0; j < 512; ++j) a = __builtin_fmaf(a, hm, hc);
      if ((i & 7) == 0) {
        unsigned d = __hip_atomic_load(dp, __ATOMIC_RELAXED, __HIP_MEMORY_SCOPE_AGENT);
        if (d >= (unsigned)NBLK) break;
        if (i > (1l << 20)) break;  // backstop: no hang
      }
    }
    asm volatile("" :: "v"(a));
    return;
  }

  // ---------------- WORKER ----------------
  unsigned* ring32 = (unsigned*)(wsb + WS_RING);
  const int c0 = blk * CPB;
  const int w = tid >> 6;        // wave 0..3 -> A rows 16w..16w+15
  const int l16 = lane & 15;
  const int g16 = lane >> 4;
  const int cc = l16 & 7;
  const bool lo = (l16 < 8);

  // Stage W once (fragment-linear, conflict-free b128) -> 256 VGPRs/lane.
  for (int idx = tid; idx < GCPB * (D_N + H_N); idx += NTHR) {
    int k = idx >> 5;
    int cl = idx & 31;
    const float* wsrc = (cl < 8) ? Wf : (cl < 16) ? Wi : (cl < 24) ? Wg : Wo;
    float v = wsrc[(size_t)k * H_N + c0 + (cl & 7)];
    int pos = ((k >> 5) * 1024) + ((cl >> 4) * 512) + (((k >> 3) & 3) * 128) + ((cl & 15) * 8) + (k & 7);
    Wl[pos] = f2bf(v);
  }
  const float bias0 = lo ? bF[c0 + cc] : bI[c0 + cc];
  const float bias1 = lo ? bG[c0 + cc] : bO[c0 + cc];
  __syncthreads();

  const int arow = 16 * w + l16;
  const int kg = 8 * g16;
  const int lofs8 = lane * 8;
  const bool owner = (arow == blk);  // 4 lanes of one wave own out-row blk

  bf16x8 wb0[32], wb1[32];
#pragma unroll
  for (int K = 0; K < 32; ++K) {
    wb0[K] = *(const bf16x8*)&Wl[K * 1024 + lofs8];
    wb1[K] = *(const bf16x8*)&Wl[K * 1024 + 512 + lofs8];
  }

  float cst[4] = {0.f, 0.f, 0.f, 0.f};
  float hT_local[4] = {0.f, 0.f, 0.f, 0.f};

  bf16x8 xa[16];
  load_x_tile(Xb, X, 0, arow, kg, xa);

  for (int t = 0; t < T_N; ++t) {
    const int slotR = (t + 1) & 1;
    const int slotW = t & 1;

    // ---- x MFMAs (prefetched xa; overlaps other blocks' skew)
    f32x4 x0a = {0,0,0,0}, x0b = {0,0,0,0}, x1a = {0,0,0,0}, x1b = {0,0,0,0};
#pragma unroll
    for (int kk = 0; kk < 8; ++kk) {
      x0a = __builtin_amdgcn_mfma_f32_16x16x32_bf16(xa[kk], wb0[kk], x0a, 0, 0, 0);
      x1a = __builtin_amdgcn_mfma_f32_16x16x32_bf16(xa[kk], wb1[kk], x1a, 0, 0, 0);
    }
#pragma unroll
    for (int kk = 8; kk < 16; ++kk) {
      x0b = __builtin_amdgcn_mfma_f32_16x16x32_bf16(xa[kk], wb0[kk], x0b, 0, 0, 0);
      x1b = __builtin_amdgcn_mfma_f32_16x16x32_bf16(xa[kk], wb1[kk], x1b, 0, 0, 0);
    }

    // ---- tagged poll + load fused: q[64] u64 = 2x(bf16|tag<<16) each.
    // Lane's kk-th quad comes from producer block 4kk+g16, row arow.
    unsigned long long q[64];
    f32x4 m0v, m1v;
    if (t > 0) {
      const unsigned tag = (unsigned)t;  // h_{t-1} carries tag t
      const unsigned long long pat = ((unsigned long long)tag << 16) | ((unsigned long long)tag << 48);
      const unsigned long long msk = 0xFFFF0000FFFF0000ull;
      const unsigned* rb = ring32 + (size_t)slotR * RING_SLOT_U32 + arow * 8;
      unsigned pend = 0xFFFFu;
      long guard = 0;
      for (;;) {
        // issue all pending quads (independent loads -> RTs overlap)
#pragma unroll
        for (int kk = 0; kk < 16; ++kk) {
          if (pend & (1u << kk)) {
            const unsigned long long* bp = (const unsigned long long*)(rb + (4 * kk + g16) * 512);
            q[4*kk+0] = __hip_atomic_load(bp + 0, __ATOMIC_RELAXED, __HIP_MEMORY_SCOPE_AGENT);
            q[4*kk+1] = __hip_atomic_load(bp + 1, __ATOMIC_RELAXED, __HIP_MEMORY_SCOPE_AGENT);
            q[4*kk+2] = __hip_atomic_load(bp + 2, __ATOMIC_RELAXED, __HIP_MEMORY_SCOPE_AGENT);
            q[4*kk+3] = __hip_atomic_load(bp + 3, __ATOMIC_RELAXED, __HIP_MEMORY_SCOPE_AGENT);
          }
        }
        // check tags
#pragma unroll
        for (int kk = 0; kk < 16; ++kk) {
          if (pend & (1u << kk)) {
            bool ok = (((q[4*kk+0] ^ pat) & msk) == 0ull) &
                      (((q[4*kk+1] ^ pat) & msk) == 0ull) &
                      (((q[4*kk+2] ^ pat) & msk) == 0ull) &
                      (((q[4*kk+3] ^ pat) & msk) == 0ull);
            if (ok) pend &= ~(1u << kk);
          }
        }
        if (!__any((int)(pend != 0u))) break;
        if (++guard > (1l << 20)) break;  // backstop: no hang
      }

      // ---- h MFMAs (unpack low-16s -> bf16x8 fragments)
      f32x4 h0a = {0,0,0,0}, h0b = {0,0,0,0}, h1a = {0,0,0,0}, h1b = {0,0,0,0};
#pragma unroll
      for (int kk = 0; kk < 8; ++kk) {
        union { unsigned u[4]; bf16x8 v; } f;
#pragma unroll
        for (int j = 0; j < 4; ++j) {
          union { unsigned long long qq; unsigned u[2]; } s; s.qq = q[4*kk+j];
          f.u[j] = (s.u[0] & 0xFFFFu) | (s.u[1] << 16);
        }
        h0a = __builtin_amdgcn_mfma_f32_16x16x32_bf16(f.v, wb0[16 + kk], h0a, 0, 0, 0);
        h1a = __builtin_amdgcn_mfma_f32_16x16x32_bf16(f.v, wb1[16 + kk], h1a, 0, 0, 0);
      }
#pragma unroll
      for (int kk = 8; kk < 16; ++kk) {
        union { unsigned u[4]; bf16x8 v; } f;
#pragma unroll
        for (int j = 0; j < 4; ++j) {
          union { unsigned long long qq; unsigned u[2]; } s; s.qq = q[4*kk+j];
          f.u[j] = (s.u[0] & 0xFFFFu) | (s.u[1] << 16);
        }
        h0b = __builtin_amdgcn_mfma_f32_16x16x32_bf16(f.v, wb0[16 + kk], h0b, 0, 0, 0);
        h1b = __builtin_amdgcn_mfma_f32_16x16x32_bf16(f.v, wb1[16 + kk], h1b, 0, 0, 0);
      }
      m0v = (x0a + x0b) + (h0a + h0b);
      m1v = (x1a + x1b) + (h1a + h1b);
    } else {
      m0v = x0a + x0b;  // h_{-1} = 0
      m1v = x1a + x1b;
    }

    // ---- gates + cell update (hv identical in lo/hi partner lanes)
    float hv[4];
#pragma unroll
    for (int r = 0; r < 4; ++r) {
      float m0 = m0v[r] + bias0;
      float m1 = m1v[r] + bias1;
      float p0 = __shfl_xor(m0, 8, 64);
      float p1 = __shfl_xor(m1, 8, 64);
      float fv = lo ? m0 : p0;
      float iv = lo ? p0 : m0;
      float gv = lo ? m1 : p1;
      float ov = lo ? p1 : m1;
      float f = sigf(fv), i = sigf(iv), g = tanhfast(gv), o = sigf(ov);
      float c = f * cst[r] + i * g;
      cst[r] = c;
      hv[r] = o * tanhfast(c);
    }

    // ---- publish h_t: tagged u32 stores, NO drain, NO flag.
    // lo lanes store rows r=0,1; hi lanes rows r=2,3 (same values).
    {
      unsigned* wbase = ring32 + (size_t)slotW * RING_SLOT_U32 + blk * 512;
      const unsigned tagw = ((unsigned)(t + 1)) << 16;
      const int r0 = lo ? 0 : 2;
#pragma unroll
      for (int rr = 0; rr < 2; ++rr) {
        int r = r0 + rr;
        int row = 16 * w + 4 * g16 + r;
        unsigned val = (unsigned)f2bf(hv[r]) | tagw;
        __hip_atomic_store(wbase + row * 8 + cc, val,
                           __ATOMIC_RELAXED, __HIP_MEMORY_SCOPE_AGENT);
      }
    }

    // ---- prefetch next x tile (consumed at next step's start)
    if (t + 1 < T_N) load_x_tile(Xb, X, t + 1, arow, kg, xa);

    // ---- consumer-side out[t-1] full-row write (off critical path)
    if (owner && t > 0) {
      float* oprev = out + (size_t)(t - 1) * (B_N * H_N) + (size_t)blk * H_N + kg;
#pragma unroll
      for (int kk = 0; kk < 16; ++kk) {
        union { unsigned long long qq; unsigned u[2]; } s0, s1, s2, s3;
        s0.qq = q[4*kk+0]; s1.qq = q[4*kk+1]; s2.qq = q[4*kk+2]; s3.qq = q[4*kk+3];
        float4 f0, f1;
        f0.x = bf2f((unsigned short)s0.u[0]); f0.y = bf2f((unsigned short)s0.u[1]);
        f0.z = bf2f((unsigned short)s1.u[0]); f0.w = bf2f((unsigned short)s1.u[1]);
        f1.x = bf2f((unsigned short)s2.u[0]); f1.y = bf2f((unsigned short)s2.u[1]);
        f1.z = bf2f((unsigned short)s3.u[0]); f1.w = bf2f((unsigned short)s3.u[1]);
        *(float4*)(oprev + 32 * kk) = f0;
        *(float4*)(oprev + 32 * kk + 4) = f1;
      }
    }

    // ---- final step: producer writes out[T-1] + keeps hT
    if (t == T_N - 1) {
      float* obase = out + (size_t)t * (B_N * H_N);
#pragma unroll
      for (int r = 0; r < 4; ++r) {
        int row = 16 * w + 4 * g16 + r;
        if (lo) obase[(size_t)row * H_N + c0 + cc] = hv[r];
        hT_local[r] = hv[r];
      }
    }
  }

  // ---- final hT / cT
  if (lo) {
#pragma unroll
    for (int r = 0; r < 4; ++r) {
      int row = 16 * w + 4 * g16 + r;
      out[HT_OFF + (size_t)row * H_N + c0 + cc] = hT_local[r];
      out[CT_OFF + (size_t)row * H_N + c0 + cc] = cst[r];
    }
  }
  __syncthreads();
  if (tid == 0)
    __hip_atomic_fetch_add((unsigned*)(wsb + WS_DONE), 1u,
                           __ATOMIC_RELAXED, __HIP_MEMORY_SCOPE_AGENT);
}

extern "C" void kernel_launch(void* const* d_in, const int* in_sizes, int n_in,
                              void* d_out, int out_size, void* d_ws, size_t ws_size,
                              hipStream_t stream) {
  const float* X  = (const float*)d_in[0];
  const float* Wf = (const float*)d_in[1];
  const float* bF = (const float*)d_in[2];
  const float* Wi = (const float*)d_in[3];
  const float* bI = (const float*)d_in[4];
  const float* Wg = (const float*)d_in[5];
  const float* bG = (const float*)d_in[6];
  const float* Wo = (const float*)d_in[7];
  const float* bO = (const float*)d_in[8];
  float* out = (float*)d_out;

  unsigned char* ws = (unsigned char*)d_ws;
  const size_t need_xb = WS_XB + (size_t)T_N * B_N * D_N * 2;  // ~129 MB
  unsigned short* Xb = (ws_size >= need_xb) ? (unsigned short*)(ws + WS_XB) : nullptr;

  init_ws_kernel<<<dim3(512), dim3(256), 0, stream>>>((unsigned*)ws);
  if (Xb) {
    xconv_kernel<<<dim3((T_N * B_N * D_N) / 8 / 256), dim3(256), 0, stream>>>(X, Xb);
  }
  lstm_kernel<<<dim3(NBLK + NHEAT), dim3(NTHR), 0, stream>>>(
      X, Xb, Wf, bF, Wi, bI, Wg, bG, Wo, bO, ws, out);
}

// Round 8
// 12209.558 us; speedup vs baseline: 3.5616x; 1.9602x over previous
//
#include <hip/hip_runtime.h>
#include <hip/hip_bf16.h>

// LSTM T=2048, B=64, D=512, H=512. Persistent kernel: 256 blocks x 256 thr.
// Blocks 0..63 = workers (block b owns hidden cols [8b,8b+8) -> 32 gate cols;
// W in registers; c-state in regs). Blocks 64..255 = heaters (hold DPM clocks,
// R5: +40%). h exchange: 2-slot bf16 mirror ring (sc1 atomics) + flag poll
// (R5 structure). KEY R8 CHANGE: fp32 `out` is written PRODUCER-side as
// u64 (bf16<<16 bit patterns == exact fp32 values), issued right before the
// single vmcnt(0) drain -- the consumer-side out pass of R5 poisoned every
// step's release with an HBM-store drain (vmcnt retires in issue order).
// Per-step wave stream: xMFMA -> poll -> 32 h-loads -> 4 stores -> vmcnt(0)
// -> flag -> x-prefetch. No RMWs (R6 lesson), no tagged-data polling (R7).

#define T_N 2048
#define B_N 64
#define D_N 512
#define H_N 512
#define NBLK 64
#define NHEAT 192
#define CPB 8
#define GCPB 32
#define NTHR 256
#define BH (B_N * H_N)

#define STACK_ELEMS ((size_t)T_N * B_N * H_N)   // 67108864
#define HT_OFF STACK_ELEMS
#define CT_OFF (STACK_ELEMS + (size_t)B_N * H_N)

// ws layout (bytes)
#define WS_DONE 0
#define WS_FLAGS 1024            // 64 blocks x 16B (4 wave-flags)
#define WS_MIRROR 32768          // 2 slots x 64KB bf16 ring [slot][prod][row][col]
#define WS_XB 262144

typedef __attribute__((ext_vector_type(4))) float f32x4;
typedef __attribute__((ext_vector_type(8))) short bf16x8;

__device__ __forceinline__ unsigned short f2bf(float f) {
  union { __hip_bfloat16 h; unsigned short u; } u;
  u.h = __float2bfloat16(f);
  return u.u;
}
__device__ __forceinline__ float sigf(float x) { return 1.0f / (1.0f + __expf(-x)); }
__device__ __forceinline__ float tanhfast(float x) { return 1.0f - 2.0f / (__expf(2.0f * x) + 1.0f); }

__global__ void init_ws_kernel(unsigned* ws32) {
  int i = blockIdx.x * blockDim.x + threadIdx.x;
  if (i < 65536) ws32[i] = 0u;  // zero done + flags + mirror (256 KB)
}

__global__ void xconv_kernel(const float* __restrict__ X, unsigned short* __restrict__ Xb) {
  size_t i = ((size_t)blockIdx.x * blockDim.x + threadIdx.x) * 8;
  float4 v0 = *(const float4*)(X + i);
  float4 v1 = *(const float4*)(X + i + 4);
  bf16x8 o;
  o[0] = (short)f2bf(v0.x); o[1] = (short)f2bf(v0.y);
  o[2] = (short)f2bf(v0.z); o[3] = (short)f2bf(v0.w);
  o[4] = (short)f2bf(v1.x); o[5] = (short)f2bf(v1.y);
  o[6] = (short)f2bf(v1.z); o[7] = (short)f2bf(v1.w);
  *(bf16x8*)(Xb + i) = o;
}

__device__ __forceinline__ void load_x_tile(const unsigned short* Xb, const float* X,
                                            int t, int arow, int kg, bf16x8 (&xa)[16]) {
  if (Xb) {
    const unsigned short* xp = Xb + ((size_t)t * B_N + arow) * D_N + kg;
#pragma unroll
    for (int kk = 0; kk < 16; ++kk) xa[kk] = *(const bf16x8*)(xp + kk * 32);
  } else {
    const float* xp = X + ((size_t)t * B_N + arow) * D_N + kg;
#pragma unroll
    for (int kk = 0; kk < 16; ++kk) {
      float4 v0 = *(const float4*)(xp + kk * 32);
      float4 v1 = *(const float4*)(xp + kk * 32 + 4);
      bf16x8 a;
      a[0] = (short)f2bf(v0.x); a[1] = (short)f2bf(v0.y);
      a[2] = (short)f2bf(v0.z); a[3] = (short)f2bf(v0.w);
      a[4] = (short)f2bf(v1.x); a[5] = (short)f2bf(v1.y);
      a[6] = (short)f2bf(v1.z); a[7] = (short)f2bf(v1.w);
      xa[kk] = a;
    }
  }
}

__global__ __launch_bounds__(NTHR, 1) void lstm_kernel(
    const float* __restrict__ X, const unsigned short* __restrict__ Xb,
    const float* __restrict__ Wf, const float* __restrict__ bF,
    const float* __restrict__ Wi, const float* __restrict__ bI,
    const float* __restrict__ Wg, const float* __restrict__ bG,
    const float* __restrict__ Wo, const float* __restrict__ bO,
    unsigned char* wsb, float* __restrict__ out) {
  __shared__ unsigned short Wl[GCPB * (D_N + H_N)];  // 64 KB staging (workers)

  const int tid = threadIdx.x;
  const int blk = blockIdx.x;
  const int lane = tid & 63;

  if (blk >= NBLK) {
    // ---------------- HEATER: hold DPM clocks; exit on done-counter ---------
    const unsigned* dp = (const unsigned*)(wsb + WS_DONE);
    float a = 1.0f + (float)(blk * NTHR + tid) * 1e-7f;
    const float hm = 0.99993f, hc = 1e-8f;
    for (long i = 0;; ++i) {
#pragma unroll
      for (int j = 0; j < 512; ++j) a = __builtin_fmaf(a, hm, hc);
      if ((i & 7) == 0) {
        unsigned d = __hip_atomic_load(dp, __ATOMIC_RELAXED, __HIP_MEMORY_SCOPE_AGENT);
        if (d >= (unsigned)NBLK) break;
        if (i > (1l << 20)) break;  // backstop: no hang
      }
    }
    asm volatile("" :: "v"(a));
    return;
  }

  // ---------------- WORKER ----------------
  const int c0 = blk * CPB;
  const int w = tid >> 6;        // wave 0..3 -> A rows 16w..16w+15
  const int l16 = lane & 15;
  const int g16 = lane >> 4;
  const int cc = l16 & 7;
  const bool lo = (l16 < 8);

  // Stage W once (fragment-linear, conflict-free b128) -> registers.
  for (int idx = tid; idx < GCPB * (D_N + H_N); idx += NTHR) {
    int k = idx >> 5;
    int cl = idx & 31;
    const float* wsrc = (cl < 8) ? Wf : (cl < 16) ? Wi : (cl < 24) ? Wg : Wo;
    float v = wsrc[(size_t)k * H_N + c0 + (cl & 7)];
    int pos = ((k >> 5) * 1024) + ((cl >> 4) * 512) + (((k >> 3) & 3) * 128) + ((cl & 15) * 8) + (k & 7);
    Wl[pos] = f2bf(v);
  }
  const float bias0 = lo ? bF[c0 + cc] : bI[c0 + cc];
  const float bias1 = lo ? bG[c0 + cc] : bO[c0 + cc];
  __syncthreads();

  const int arow = 16 * w + l16;
  const int kg = 8 * g16;
  const int lofs8 = lane * 8;

  bf16x8 wb0[32], wb1[32];
#pragma unroll
  for (int K = 0; K < 32; ++K) {
    wb0[K] = *(const bf16x8*)&Wl[K * 1024 + lofs8];
    wb1[K] = *(const bf16x8*)&Wl[K * 1024 + 512 + lofs8];
  }

  unsigned* flags = (unsigned*)(wsb + WS_FLAGS);
  float cst[4] = {0.f, 0.f, 0.f, 0.f};
  float hT_local[4] = {0.f, 0.f, 0.f, 0.f};

  bf16x8 xa[16];
  load_x_tile(Xb, X, 0, arow, kg, xa);

  for (int t = 0; t < T_N; ++t) {
    const int slotR = (t + 1) & 1;
    const int slotW = t & 1;

    // ---- x MFMAs (prefetched xa)
    f32x4 x0a = {0,0,0,0}, x0b = {0,0,0,0}, x1a = {0,0,0,0}, x1b = {0,0,0,0};
#pragma unroll
    for (int kk = 0; kk < 8; ++kk) {
      x0a = __builtin_amdgcn_mfma_f32_16x16x32_bf16(xa[kk], wb0[kk], x0a, 0, 0, 0);
      x1a = __builtin_amdgcn_mfma_f32_16x16x32_bf16(xa[kk], wb1[kk], x1a, 0, 0, 0);
    }
#pragma unroll
    for (int kk = 8; kk < 16; ++kk) {
      x0b = __builtin_amdgcn_mfma_f32_16x16x32_bf16(xa[kk], wb0[kk], x0b, 0, 0, 0);
      x1b = __builtin_amdgcn_mfma_f32_16x16x32_bf16(xa[kk], wb1[kk], x1b, 0, 0, 0);
    }

    f32x4 m0v, m1v;
    if (t > 0) {
      // ---- per-wave poll: lane j checks block j's 4 wave-flags (16B packed)
      {
        const unsigned tgt = (unsigned)t;
        const unsigned long long* fp = (const unsigned long long*)flags + (size_t)lane * 2;
        long guard = 0;
        for (;;) {
          unsigned long long q0 = __hip_atomic_load(fp, __ATOMIC_RELAXED, __HIP_MEMORY_SCOPE_AGENT);
          unsigned long long q1 = __hip_atomic_load(fp + 1, __ATOMIC_RELAXED, __HIP_MEMORY_SCOPE_AGENT);
          unsigned a0 = (unsigned)q0, a1 = (unsigned)(q0 >> 32);
          unsigned a2 = (unsigned)q1, a3 = (unsigned)(q1 >> 32);
          bool ok = (a0 >= tgt) && (a1 >= tgt) && (a2 >= tgt) && (a3 >= tgt);
          if (__all((int)ok)) break;
          __builtin_amdgcn_s_sleep(1);
          if (++guard > (1l << 22)) break;  // bail-out: no deadlock-hang
        }
      }

      // ---- 32 h-loads, one batch. Mirror ring [slot][prod][row][8col] bf16.
      unsigned long long hq0[16], hq1[16];
      {
        const unsigned long long* hbase =
            (const unsigned long long*)(wsb + WS_MIRROR + (size_t)slotR * 65536);
#pragma unroll
        for (int kk = 0; kk < 16; ++kk) {
          const unsigned long long* hp = hbase + (size_t)(g16 + 4 * kk) * 128 + arow * 2;
          hq0[kk] = __hip_atomic_load(hp, __ATOMIC_RELAXED, __HIP_MEMORY_SCOPE_AGENT);
          hq1[kk] = __hip_atomic_load(hp + 1, __ATOMIC_RELAXED, __HIP_MEMORY_SCOPE_AGENT);
        }
      }

      // ---- h MFMAs
      f32x4 h0a = {0,0,0,0}, h0b = {0,0,0,0}, h1a = {0,0,0,0}, h1b = {0,0,0,0};
#pragma unroll
      for (int kk = 0; kk < 8; ++kk) {
        union { unsigned long long q[2]; bf16x8 v; } u;
        u.q[0] = hq0[kk]; u.q[1] = hq1[kk];
        h0a = __builtin_amdgcn_mfma_f32_16x16x32_bf16(u.v, wb0[16 + kk], h0a, 0, 0, 0);
        h1a = __builtin_amdgcn_mfma_f32_16x16x32_bf16(u.v, wb1[16 + kk], h1a, 0, 0, 0);
      }
#pragma unroll
      for (int kk = 8; kk < 16; ++kk) {
        union { unsigned long long q[2]; bf16x8 v; } u;
        u.q[0] = hq0[kk]; u.q[1] = hq1[kk];
        h0b = __builtin_amdgcn_mfma_f32_16x16x32_bf16(u.v, wb0[16 + kk], h0b, 0, 0, 0);
        h1b = __builtin_amdgcn_mfma_f32_16x16x32_bf16(u.v, wb1[16 + kk], h1b, 0, 0, 0);
      }
      m0v = (x0a + x0b) + (h0a + h0b);
      m1v = (x1a + x1b) + (h1a + h1b);
    } else {
      m0v = x0a + x0b;  // h_{-1} = 0
      m1v = x1a + x1b;
    }

    // ---- gates + cell update (hv identical in lo/hi partner lanes)
    float hv[4];
#pragma unroll
    for (int r = 0; r < 4; ++r) {
      float m0 = m0v[r] + bias0;
      float m1 = m1v[r] + bias1;
      float p0 = __shfl_xor(m0, 8, 64);
      float p1 = __shfl_xor(m1, 8, 64);
      float fv = lo ? m0 : p0;
      float iv = lo ? p0 : m0;
      float gv = lo ? m1 : p1;
      float ov = lo ? p1 : m1;
      float f = sigf(fv), i = sigf(iv), g = tanhfast(gv), o = sigf(ov);
      float c = f * cst[r] + i * g;
      cst[r] = c;
      hv[r] = o * tanhfast(c);
    }

    // ---- publish h_t: mirror (bf16 pair, sc1) + out fp32 pair (bf16<<16,
    // plain store -> L2 ack, merged at MALL). lo lanes rows r=0,1; hi r=2,3.
    {
      unsigned* mrb = (unsigned*)(wsb + WS_MIRROR + (size_t)slotW * 65536) + blk * 256;
      float* outt = out + (size_t)t * BH + c0;
#pragma unroll
      for (int r = 0; r < 4; ++r) {
        int row = 16 * w + 4 * g16 + r;
        unsigned short hb = f2bf(hv[r]);
        unsigned opp = __shfl_xor((unsigned)hb, 1, 64);
        bool mine = ((cc & 1) == 0) && (lo ? (r < 2) : (r >= 2));
        if (mine) {
          unsigned pack = (unsigned)hb | (opp << 16);
          __hip_atomic_store(mrb + row * 4 + (cc >> 1), pack,
                             __ATOMIC_RELAXED, __HIP_MEMORY_SCOPE_AGENT);
          unsigned long long ov = ((unsigned long long)((unsigned)hb << 16)) |
                                  (((unsigned long long)(opp << 16)) << 32);
          *(unsigned long long*)(outt + (size_t)row * H_N + cc) = ov;
        }
      }
    }

    // ---- release: drain ONLY this step's 4 stores, then set wave flag
    asm volatile("s_waitcnt vmcnt(0)" ::: "memory");
    if (lane == 0) {
      __hip_atomic_store(flags + blk * 4 + w, (unsigned)(t + 1),
                         __ATOMIC_RELAXED, __HIP_MEMORY_SCOPE_AGENT);
    }

    // ---- prefetch next x tile (completes during next step)
    if (t + 1 < T_N) load_x_tile(Xb, X, t + 1, arow, kg, xa);

    if (t == T_N - 1) {
#pragma unroll
      for (int r = 0; r < 4; ++r) hT_local[r] = hv[r];
    }
  }

  // ---- final hT / cT
  if (lo) {
#pragma unroll
    for (int r = 0; r < 4; ++r) {
      int row = 16 * w + 4 * g16 + r;
      out[HT_OFF + (size_t)row * H_N + c0 + cc] = hT_local[r];
      out[CT_OFF + (size_t)row * H_N + c0 + cc] = cst[r];
    }
  }
  __syncthreads();
  if (tid == 0)
    __hip_atomic_fetch_add((unsigned*)(wsb + WS_DONE), 1u,
                           __ATOMIC_RELAXED, __HIP_MEMORY_SCOPE_AGENT);
}

extern "C" void kernel_launch(void* const* d_in, const int* in_sizes, int n_in,
                              void* d_out, int out_size, void* d_ws, size_t ws_size,
                              hipStream_t stream) {
  const float* X  = (const float*)d_in[0];
  const float* Wf = (const float*)d_in[1];
  const float* bF = (const float*)d_in[2];
  const float* Wi = (const float*)d_in[3];
  const float* bI = (const float*)d_in[4];
  const float* Wg = (const float*)d_in[5];
  const float* bG = (const float*)d_in[6];
  const float* Wo = (const float*)d_in[7];
  const float* bO = (const float*)d_in[8];
  float* out = (float*)d_out;

  unsigned char* ws = (unsigned char*)d_ws;
  const size_t need_xb = WS_XB + (size_t)T_N * B_N * D_N * 2;  // ~129 MB
  unsigned short* Xb = (ws_size >= need_xb) ? (unsigned short*)(ws + WS_XB) : nullptr;

  init_ws_kernel<<<dim3(256), dim3(256), 0, stream>>>((unsigned*)ws);
  if (Xb) {
    xconv_kernel<<<dim3((T_N * B_N * D_N) / 8 / 256), dim3(256), 0, stream>>>(X, Xb);
  }
  lstm_kernel<<<dim3(NBLK + NHEAT), dim3(NTHR), 0, stream>>>(
      X, Xb, Wf, bF, Wi, bI, Wg, bG, Wo, bO, ws, out);
}